// Round 1
// baseline (5118.996 us; speedup 1.0000x reference)
//
#include <hip/hip_runtime.h>
#include <math.h>

// Problem constants (from reference)
constexpr int B   = 16;
constexpr int S   = 8192;
constexpr int Dd  = 64;
constexpr int H   = 8;
constexpr int NB  = 128;       // n_buckets
constexpr int NCH = 1024;      // chunks per batch (H * NB)
constexpr float SM_SCALE = 0.125f;   // D^-0.5
constexpr float SELF_VAL = -5e4f;

// ---------------------------------------------------------------------------
// K1: LSH hashing. rotated[b,h,s,i] = sum_f qk[b,s,f] * rot[b,f,h,i]
// bucket = argmax over [rot, -rot] (first-occurrence ties). fp32 with top-2
// margin; fp64 recompute when margin < 1e-2 (matches an fp64 reference).
// ---------------------------------------------------------------------------
__global__ __launch_bounds__(256) void k_hash(const float* __restrict__ qk,
                                              const float* __restrict__ rot,
                                              int* __restrict__ buckets) {
  const int bh = blockIdx.y;           // b*8 + h
  const int b = bh >> 3, h = bh & 7;
  __shared__ float R[64][65];          // R[f][i], padded
  const int tid = threadIdx.x;
  for (int idx = tid; idx < 64 * 64; idx += 256) {
    int f = idx >> 6, i = idx & 63;
    R[f][i] = rot[(((size_t)b * 64 + f) * 8 + h) * 64 + i];
  }
  __syncthreads();
  const int s = blockIdx.x * 256 + tid;
  const float* q = qk + ((size_t)b * S + s) * 64;
  float qv[64];
#pragma unroll
  for (int f = 0; f < 64; ++f) qv[f] = q[f];

  // fp32 pass: track best/second over positives and negatives separately
  float bP = -1e30f, sP = -1e30f, bN = -1e30f, sN = -1e30f;
  int iP = 0, iN = 0;
  for (int i = 0; i < 64; ++i) {
    float acc = 0.f;
#pragma unroll
    for (int f = 0; f < 64; ++f) acc = fmaf(qv[f], R[f][i], acc);
    if (acc > bP) { sP = bP; bP = acc; iP = i; }
    else if (acc > sP) sP = acc;
    float nv = -acc;
    if (nv > bN) { sN = bN; bN = nv; iN = i; }
    else if (nv > sN) sN = nv;
  }
  // combined argmax with first-occurrence semantics: positives come first
  int bidx = (bN > bP) ? (64 + iN) : iP;
  float best = fmaxf(bP, bN);
  float second = fmaxf(fmaxf(sP, sN), fminf(bP, bN));

  if (best - second < 1e-2f) {
    // rare: decide in fp64
    double dbP = -1e300, dbN = -1e300;
    int diP = 0, diN = 0;
    for (int i = 0; i < 64; ++i) {
      double acc = 0.0;
      for (int f = 0; f < 64; ++f) acc += (double)qv[f] * (double)R[f][i];
      if (acc > dbP) { dbP = acc; diP = i; }
      if (-acc > dbN) { dbN = -acc; diN = i; }
    }
    bidx = (dbN > dbP) ? (64 + diN) : diP;
  }
  buckets[(size_t)bh * S + s] = bidx;
}

// ---------------------------------------------------------------------------
// K2: stable counting sort per (b,h): 8192 items, 128 buckets, 1 wave.
// st[bh][pos] = original position t, sorted by (bucket, t).
// ---------------------------------------------------------------------------
__global__ __launch_bounds__(64) void k_sort(const int* __restrict__ buckets,
                                             int* __restrict__ st) {
  const int bh = blockIdx.x;
  __shared__ int hist[128][65];   // hist[bucket][thread], padded
  __shared__ int base[128];
  const int t = threadIdx.x;
  for (int v = 0; v < 128; ++v) hist[v][t] = 0;
  __syncthreads();
  const int* bk = buckets + (size_t)bh * S;
  // phase A: per-thread local histogram over its contiguous 128 items
  for (int k = 0; k < 128; ++k) {
    int v = bk[t * 128 + k];
    hist[v][t]++;
  }
  __syncthreads();
  // phase B: per-bucket exclusive prefix over threads; totals into base[]
  for (int v = t; v < 128; v += 64) {
    int run = 0;
    for (int tt = 0; tt < 64; ++tt) {
      int x = hist[v][tt]; hist[v][tt] = run; run += x;
    }
    base[v] = run;
  }
  __syncthreads();
  if (t == 0) {
    int run = 0;
    for (int v = 0; v < 128; ++v) { int x = base[v]; base[v] = run; run += x; }
  }
  __syncthreads();
  // phase C: stable placement
  int* out = st + (size_t)bh * S;
  for (int k = 0; k < 128; ++k) {
    int item = t * 128 + k;
    int v = bk[item];
    int pos = base[v] + hist[v][t]++;
    out[pos] = item;
  }
}

// ---------------------------------------------------------------------------
// Helper: compute gathered token index for column j of chunk c
// ---------------------------------------------------------------------------
__device__ __forceinline__ int col_token(const int* __restrict__ st, int b,
                                         int c, int j) {
  int cc = (j < 64) ? c : ((c + NCH - 1) & (NCH - 1));
  int r = j & 63;
  int h = cc >> 7;
  int slot = ((cc & 127) << 6) + r;
  return st[((size_t)b * H + h) * S + slot];
}

// ---------------------------------------------------------------------------
// K3a: per-chunk QK^T + mask + logsumexp; scatter lse to [B,H,S]
// ---------------------------------------------------------------------------
__global__ __launch_bounds__(256) void k_att1(const float* __restrict__ qk,
                                              const int* __restrict__ st,
                                              float* __restrict__ lse_buf) {
  const int c = blockIdx.x;   // chunk 0..1023
  const int b = blockIdx.y;
  const int tid = threadIdx.x;
  __shared__ float Km[128][68];   // raw gathered qk rows (cols); rows = first 64
  __shared__ float scale[128];    // 1/max(norm,1e-12)
  __shared__ int   tj[128];
  __shared__ float m4[64][4], s4[64][4];

  if (tid < 128) tj[tid] = col_token(st, b, c, tid);
  __syncthreads();
  {
    int j = tid >> 1, part = tid & 1;
    const float4* src = (const float4*)(qk + ((size_t)b * S + tj[j]) * 64 + part * 32);
    float4* dst = (float4*)&Km[j][part * 32];
#pragma unroll
    for (int x = 0; x < 8; ++x) dst[x] = src[x];
  }
  __syncthreads();
  if (tid < 128) {
    float s = 0.f;
#pragma unroll
    for (int f = 0; f < 64; ++f) { float x = Km[tid][f]; s = fmaf(x, x, s); }
    scale[tid] = 1.0f / fmaxf(sqrtf(s), 1e-12f);
  }
  __syncthreads();

  const int r = tid & 63, cg = tid >> 6;
  float qreg[64];
#pragma unroll
  for (int x = 0; x < 16; ++x) ((float4*)qreg)[x] = *(const float4*)&Km[r][x * 4];
  const int t_r = tj[r];

  float dv[32];
#pragma unroll 4
  for (int cc = 0; cc < 32; ++cc) {
    const int col = cg * 32 + cc;
    float acc = 0.f;
#pragma unroll
    for (int f = 0; f < 64; ++f) acc = fmaf(qreg[f], Km[col][f], acc);
    float val = acc * (scale[col] * SM_SCALE);
    if (tj[col] == t_r) val = SELF_VAL;
    dv[cc] = val;
  }
  float m = -1e30f;
#pragma unroll
  for (int cc = 0; cc < 32; ++cc) m = fmaxf(m, dv[cc]);
  float se = 0.f;
#pragma unroll
  for (int cc = 0; cc < 32; ++cc) se += expf(dv[cc] - m);
  m4[r][cg] = m; s4[r][cg] = se;
  __syncthreads();
  if (cg == 0) {
    float mm = m4[r][0];
    for (int g = 1; g < 4; ++g) mm = fmaxf(mm, m4[r][g]);
    float ss = 0.f;
    for (int g = 0; g < 4; ++g) ss += s4[r][g] * expf(m4[r][g] - mm);
    float lse = mm + logf(ss);
    int h = c >> 7;
    lse_buf[((size_t)b * H + h) * S + t_r] = lse;
  }
}

// ---------------------------------------------------------------------------
// K4: per-token softmax weights across the 8 hash rounds
// ---------------------------------------------------------------------------
__global__ __launch_bounds__(256) void k_weights(const float* __restrict__ lse_buf,
                                                 float* __restrict__ w_buf) {
  const int idx = blockIdx.x * 256 + threadIdx.x;   // b*S + t
  const int b = idx >> 13, t = idx & (S - 1);
  float l[8];
#pragma unroll
  for (int h = 0; h < 8; ++h) l[h] = lse_buf[((size_t)b * H + h) * S + t];
  float m = l[0];
#pragma unroll
  for (int h = 1; h < 8; ++h) m = fmaxf(m, l[h]);
  float s = 0.f;
#pragma unroll
  for (int h = 0; h < 8; ++h) s += expf(l[h] - m);
  float inv = 1.0f / s;
#pragma unroll
  for (int h = 0; h < 8; ++h)
    w_buf[((size_t)b * H + h) * S + t] = expf(l[h] - m) * inv;
}

// ---------------------------------------------------------------------------
// K3b: recompute dots, probs = exp(d - lse), PV, scale by round weight,
// atomicAdd-scatter into out[b, t, :]
// ---------------------------------------------------------------------------
__global__ __launch_bounds__(256) void k_att2(const float* __restrict__ qk,
                                              const float* __restrict__ v,
                                              const int* __restrict__ st,
                                              const float* __restrict__ lse_buf,
                                              const float* __restrict__ w_buf,
                                              float* __restrict__ out) {
  const int c = blockIdx.x;
  const int b = blockIdx.y;
  const int tid = threadIdx.x;
  const int h = c >> 7;
  __shared__ float Km[128][68];
  __shared__ float Vm[128][68];
  __shared__ float scale[128];
  __shared__ int   tj[128];
  __shared__ float Pr[64][129];

  if (tid < 128) tj[tid] = col_token(st, b, c, tid);
  __syncthreads();
  {
    int j = tid >> 1, part = tid & 1;
    size_t row = (size_t)b * S + tj[j];
    const float4* srcK = (const float4*)(qk + row * 64 + part * 32);
    const float4* srcV = (const float4*)(v + row * 64 + part * 32);
    float4* dstK = (float4*)&Km[j][part * 32];
    float4* dstV = (float4*)&Vm[j][part * 32];
#pragma unroll
    for (int x = 0; x < 8; ++x) { dstK[x] = srcK[x]; dstV[x] = srcV[x]; }
  }
  __syncthreads();
  if (tid < 128) {
    float s = 0.f;
#pragma unroll
    for (int f = 0; f < 64; ++f) { float x = Km[tid][f]; s = fmaf(x, x, s); }
    scale[tid] = 1.0f / fmaxf(sqrtf(s), 1e-12f);
  }
  __syncthreads();

  {
    const int r = tid & 63, cg = tid >> 6;
    float qreg[64];
#pragma unroll
    for (int x = 0; x < 16; ++x) ((float4*)qreg)[x] = *(const float4*)&Km[r][x * 4];
    const int t_r = tj[r];
    const float lse = lse_buf[((size_t)b * H + h) * S + t_r];
#pragma unroll 4
    for (int cc = 0; cc < 32; ++cc) {
      const int col = cg * 32 + cc;
      float acc = 0.f;
#pragma unroll
      for (int f = 0; f < 64; ++f) acc = fmaf(qreg[f], Km[col][f], acc);
      float val = acc * (scale[col] * SM_SCALE);
      if (tj[col] == t_r) val = SELF_VAL;
      Pr[r][col] = expf(val - lse);
    }
  }
  __syncthreads();

  // PV: thread -> (row rr, 16-wide d-group dg)
  const int rr = tid >> 2, dg = tid & 3;
  float acc[16];
#pragma unroll
  for (int k = 0; k < 16; ++k) acc[k] = 0.f;
#pragma unroll 4
  for (int col = 0; col < 128; ++col) {
    float p = Pr[rr][col];
    const float4* vp = (const float4*)&Vm[col][dg * 16];
#pragma unroll
    for (int x = 0; x < 4; ++x) {
      float4 vv = vp[x];
      acc[x * 4 + 0] = fmaf(p, vv.x, acc[x * 4 + 0]);
      acc[x * 4 + 1] = fmaf(p, vv.y, acc[x * 4 + 1]);
      acc[x * 4 + 2] = fmaf(p, vv.z, acc[x * 4 + 2]);
      acc[x * 4 + 3] = fmaf(p, vv.w, acc[x * 4 + 3]);
    }
  }
  const int t_rr = tj[rr];
  const float w = w_buf[((size_t)b * H + h) * S + t_rr];
  float* op = out + ((size_t)b * S + t_rr) * 64 + dg * 16;
#pragma unroll
  for (int k = 0; k < 16; ++k) atomicAdd(&op[k], acc[k] * w);
}

// ---------------------------------------------------------------------------
extern "C" void kernel_launch(void* const* d_in, const int* in_sizes, int n_in,
                              void* d_out, int out_size, void* d_ws, size_t ws_size,
                              hipStream_t stream) {
  const float* qk  = (const float*)d_in[0];
  const float* v   = (const float*)d_in[1];
  const float* rot = (const float*)d_in[2];
  float* out = (float*)d_out;
  char* ws = (char*)d_ws;

  int*   buckets = (int*)ws;                       // 4 MB
  int*   st      = (int*)(ws + ((size_t)4 << 20)); // 4 MB
  float* lse     = (float*)(ws + ((size_t)8 << 20));
  float* wbuf    = (float*)(ws + ((size_t)12 << 20));

  hipMemsetAsync(d_out, 0, (size_t)B * S * Dd * sizeof(float), stream);

  k_hash<<<dim3(S / 256, B * H), 256, 0, stream>>>(qk, rot, buckets);
  k_sort<<<B * H, 64, 0, stream>>>(buckets, st);
  k_att1<<<dim3(NCH, B), 256, 0, stream>>>(qk, st, lse);
  k_weights<<<(B * S) / 256, 256, 0, stream>>>(lse, wbuf);
  k_att2<<<dim3(NCH, B), 256, 0, stream>>>(qk, v, st, lse, wbuf, out);
}

// Round 2
// 982.909 us; speedup vs baseline: 5.2080x; 5.2080x over previous
//
#include <hip/hip_runtime.h>
#include <math.h>

constexpr int B   = 16;
constexpr int S   = 8192;
constexpr int H   = 8;
constexpr int NCH = 1024;      // chunks per batch (H * n_buckets)
constexpr float SM_SCALE = 0.125f;
constexpr float SELF_VAL = -5e4f;

typedef __bf16 bf16x8 __attribute__((ext_vector_type(8)));
typedef float  f32x4  __attribute__((ext_vector_type(4)));
union frag_u { bf16x8 v; short s[8]; };

__device__ __forceinline__ short f2bf(float x) {
  unsigned u = __float_as_uint(x);
  unsigned r = u + 0x7fffu + ((u >> 16) & 1u);
  return (short)(r >> 16);
}
__device__ __forceinline__ float bf2f(short h) {
  return __uint_as_float(((unsigned)(unsigned short)h) << 16);
}
__device__ __forceinline__ unsigned pack2(short a, short b) {
  return ((unsigned)(unsigned short)a) | (((unsigned)(unsigned short)b) << 16);
}

// ---------------------------------------------------------------------------
// K1: LSH hashing (unchanged from R1 — correct, revisit later)
// ---------------------------------------------------------------------------
__global__ __launch_bounds__(256) void k_hash(const float* __restrict__ qk,
                                              const float* __restrict__ rot,
                                              int* __restrict__ buckets) {
  const int bh = blockIdx.y;
  const int b = bh >> 3, h = bh & 7;
  __shared__ float R[64][65];
  const int tid = threadIdx.x;
  for (int idx = tid; idx < 64 * 64; idx += 256) {
    int f = idx >> 6, i = idx & 63;
    R[f][i] = rot[(((size_t)b * 64 + f) * 8 + h) * 64 + i];
  }
  __syncthreads();
  const int s = blockIdx.x * 256 + tid;
  const float* q = qk + ((size_t)b * S + s) * 64;
  float qv[64];
#pragma unroll
  for (int f = 0; f < 64; ++f) qv[f] = q[f];

  float bP = -1e30f, sP = -1e30f, bN = -1e30f, sN = -1e30f;
  int iP = 0, iN = 0;
  for (int i = 0; i < 64; ++i) {
    float acc = 0.f;
#pragma unroll
    for (int f = 0; f < 64; ++f) acc = fmaf(qv[f], R[f][i], acc);
    if (acc > bP) { sP = bP; bP = acc; iP = i; }
    else if (acc > sP) sP = acc;
    float nv = -acc;
    if (nv > bN) { sN = bN; bN = nv; iN = i; }
    else if (nv > sN) sN = nv;
  }
  int bidx = (bN > bP) ? (64 + iN) : iP;
  float best = fmaxf(bP, bN);
  float second = fmaxf(fmaxf(sP, sN), fminf(bP, bN));
  if (best - second < 1e-2f) {
    double dbP = -1e300, dbN = -1e300;
    int diP = 0, diN = 0;
    for (int i = 0; i < 64; ++i) {
      double acc = 0.0;
      for (int f = 0; f < 64; ++f) acc += (double)qv[f] * (double)R[f][i];
      if (acc > dbP) { dbP = acc; diP = i; }
      if (-acc > dbN) { dbN = -acc; diN = i; }
    }
    bidx = (dbN > dbP) ? (64 + diN) : diP;
  }
  buckets[(size_t)bh * S + s] = bidx;
}

// ---------------------------------------------------------------------------
// K2: stable counting sort per (b,h) (unchanged)
// ---------------------------------------------------------------------------
__global__ __launch_bounds__(64) void k_sort(const int* __restrict__ buckets,
                                             int* __restrict__ st) {
  const int bh = blockIdx.x;
  __shared__ int hist[128][65];
  __shared__ int base[128];
  const int t = threadIdx.x;
  for (int v = 0; v < 128; ++v) hist[v][t] = 0;
  __syncthreads();
  const int* bk = buckets + (size_t)bh * S;
  for (int k = 0; k < 128; ++k) hist[bk[t * 128 + k]][t]++;
  __syncthreads();
  for (int v = t; v < 128; v += 64) {
    int run = 0;
    for (int tt = 0; tt < 64; ++tt) { int x = hist[v][tt]; hist[v][tt] = run; run += x; }
    base[v] = run;
  }
  __syncthreads();
  if (t == 0) {
    int run = 0;
    for (int v = 0; v < 128; ++v) { int x = base[v]; base[v] = run; run += x; }
  }
  __syncthreads();
  int* out = st + (size_t)bh * S;
  for (int k = 0; k < 128; ++k) {
    int item = t * 128 + k;
    int v = bk[item];
    out[base[v] + hist[v][t]++] = item;
  }
}

__device__ __forceinline__ int col_token(const int* __restrict__ st, int b,
                                         int c, int j) {
  int cc = (j < 64) ? c : ((c + NCH - 1) & (NCH - 1));
  int r = j & 63;
  int h = cc >> 7;
  int slot = ((cc & 127) << 6) + r;
  return st[((size_t)b * H + h) * S + slot];
}

// ---------------------------------------------------------------------------
// Shared staging: gather 128 rows of qk, split fp32 -> bf16 hi/lo into LDS,
// accumulate squared norms. j = tid>>1, half = tid&1 handles 32 floats.
// ---------------------------------------------------------------------------
__device__ __forceinline__ void stage_kq(const float* __restrict__ qk, int b,
                                         const int* tjs, short (*KQh)[72],
                                         short (*KQl)[72], float (*scp)[2],
                                         int tid) {
  const int j = tid >> 1, hf = tid & 1;
  const float* src = qk + ((size_t)b * S + tjs[j]) * 64 + hf * 32;
  unsigned* dh = (unsigned*)&KQh[j][hf * 32];
  unsigned* dl = (unsigned*)&KQl[j][hf * 32];
  float ss = 0.f;
#pragma unroll
  for (int x = 0; x < 32; x += 4) {
    float4 v4 = *(const float4*)(src + x);
    const float* vf = (const float*)&v4;
    short h0 = f2bf(vf[0]), h1 = f2bf(vf[1]), h2 = f2bf(vf[2]), h3 = f2bf(vf[3]);
    float l0 = vf[0] - bf2f(h0), l1 = vf[1] - bf2f(h1);
    float l2 = vf[2] - bf2f(h2), l3 = vf[3] - bf2f(h3);
    dh[(x >> 1)]     = pack2(h0, h1);
    dh[(x >> 1) + 1] = pack2(h2, h3);
    dl[(x >> 1)]     = pack2(f2bf(l0), f2bf(l1));
    dl[(x >> 1) + 1] = pack2(f2bf(l2), f2bf(l3));
    ss = fmaf(vf[0], vf[0], ss); ss = fmaf(vf[1], vf[1], ss);
    ss = fmaf(vf[2], vf[2], ss); ss = fmaf(vf[3], vf[3], ss);
  }
  scp[j][hf] = ss;
}

#define MFMA(a, bb, c) __builtin_amdgcn_mfma_f32_16x16x32_bf16((a), (bb), (c), 0, 0, 0)

// ---------------------------------------------------------------------------
// K3a: MFMA dots + per-row logsumexp -> lse_buf[b,h,t]
// ---------------------------------------------------------------------------
__global__ __launch_bounds__(256) void k_att1(const float* __restrict__ qk,
                                              const int* __restrict__ st,
                                              float* __restrict__ lse_buf) {
  const int c = blockIdx.x, b = blockIdx.y;
  const int tid = threadIdx.x;
  __shared__ __align__(16) char smem[38912];
  short (*KQh)[72] = (short(*)[72])(smem);
  short (*KQl)[72] = (short(*)[72])(smem + 18432);
  float* scale     = (float*)(smem + 36864);
  int*   tjs       = (int*)(smem + 37376);
  float (*scp)[2]  = (float(*)[2])(smem + 37888);

  if (tid < 128) tjs[tid] = col_token(st, b, c, tid);
  __syncthreads();
  stage_kq(qk, b, tjs, KQh, KQl, scp, tid);
  __syncthreads();
  if (tid < 128)
    scale[tid] = SM_SCALE / fmaxf(sqrtf(scp[tid][0] + scp[tid][1]), 1e-12f);
  __syncthreads();

  const int w = tid >> 6, l = tid & 63, lr = l & 15, lg = l >> 4;
  f32x4 acc[8];
#pragma unroll
  for (int nt = 0; nt < 8; ++nt) acc[nt] = (f32x4){0.f, 0.f, 0.f, 0.f};
#pragma unroll
  for (int kt = 0; kt < 2; ++kt) {
    const int ko = kt * 32 + lg * 8;
    bf16x8 Ah = *(const bf16x8*)&KQh[16 * w + lr][ko];
    bf16x8 Al = *(const bf16x8*)&KQl[16 * w + lr][ko];
#pragma unroll
    for (int nt = 0; nt < 8; ++nt) {
      bf16x8 Bh = *(const bf16x8*)&KQh[16 * nt + lr][ko];
      bf16x8 Bl = *(const bf16x8*)&KQl[16 * nt + lr][ko];
      acc[nt] = MFMA(Ah, Bh, acc[nt]);
      acc[nt] = MFMA(Ah, Bl, acc[nt]);
      acc[nt] = MFMA(Al, Bh, acc[nt]);
    }
  }

  float sc8[8]; int tc8[8];
#pragma unroll
  for (int nt = 0; nt < 8; ++nt) {
    int col = 16 * nt + lr;
    sc8[nt] = scale[col]; tc8[nt] = tjs[col];
  }
  const int h = c >> 7;
#pragma unroll
  for (int r = 0; r < 4; ++r) {
    const int row = 16 * w + 4 * lg + r;
    const int trow = tjs[row];
    float v8[8]; float m = -3e38f;
#pragma unroll
    for (int nt = 0; nt < 8; ++nt) {
      float val = (tc8[nt] == trow) ? SELF_VAL : acc[nt][r] * sc8[nt];
      v8[nt] = val; m = fmaxf(m, val);
    }
#pragma unroll
    for (int dm = 1; dm < 16; dm <<= 1) m = fmaxf(m, __shfl_xor(m, dm));
    float s = 0.f;
#pragma unroll
    for (int nt = 0; nt < 8; ++nt) s += expf(v8[nt] - m);
#pragma unroll
    for (int dm = 1; dm < 16; dm <<= 1) s += __shfl_xor(s, dm);
    if (lr == 0) lse_buf[((size_t)b * H + h) * S + trow] = m + logf(s);
  }
}

// ---------------------------------------------------------------------------
// K4: L_all[b,t] = logsumexp over h of lse
// ---------------------------------------------------------------------------
__global__ __launch_bounds__(256) void k_lall(const float* __restrict__ lse_buf,
                                              float* __restrict__ lall) {
  const int idx = blockIdx.x * 256 + threadIdx.x;   // b*S + t
  const int b = idx >> 13, t = idx & (S - 1);
  float l[8];
#pragma unroll
  for (int h = 0; h < 8; ++h) l[h] = lse_buf[((size_t)b * H + h) * S + t];
  float m = l[0];
#pragma unroll
  for (int h = 1; h < 8; ++h) m = fmaxf(m, l[h]);
  float s = 0.f;
#pragma unroll
  for (int h = 0; h < 8; ++h) s += expf(l[h] - m);
  lall[idx] = m + logf(s);
}

// ---------------------------------------------------------------------------
// K3b: MFMA dots -> P = exp(val - L_all) -> MFMA PV. Epilogue: plain store to
// obuf[b,h,t,:] (combine later) or atomicAdd fallback.
// ---------------------------------------------------------------------------
__global__ __launch_bounds__(256) void k_att2(const float* __restrict__ qk,
                                              const float* __restrict__ v,
                                              const int* __restrict__ st,
                                              const float* __restrict__ lall,
                                              float* __restrict__ obuf,
                                              float* __restrict__ out) {
  const int c = blockIdx.x, b = blockIdx.y;
  const int tid = threadIdx.x;
  const int h = c >> 7;
  __shared__ __align__(16) char smem[73984];
  short (*KQh)[72]  = (short(*)[72])(smem);
  short (*KQl)[72]  = (short(*)[72])(smem + 18432);
  short (*Vth)[136] = (short(*)[136])(smem + 36864);
  short (*Vtl)[136] = (short(*)[136])(smem + 54272);
  float* scale      = (float*)(smem + 71680);
  int*   tjs        = (int*)(smem + 72192);
  float* Lr         = (float*)(smem + 72704);
  float (*scp)[2]   = (float(*)[2])(smem + 72960);
  float* Pf = (float*)smem;   // [64][132] fp32, overlays KQh+KQl after dots

  if (tid < 128) tjs[tid] = col_token(st, b, c, tid);
  __syncthreads();
  stage_kq(qk, b, tjs, KQh, KQl, scp, tid);
  // V staged transposed: Vt[d][col] bf16 hi/lo, dword-packed col pairs
  {
    const int c2 = tid & 63, wq = tid >> 6;
    const int j0 = 2 * c2, j1 = j0 + 1;
    const float* v0 = v + ((size_t)b * S + tjs[j0]) * 64 + wq * 16;
    const float* v1 = v + ((size_t)b * S + tjs[j1]) * 64 + wq * 16;
    unsigned* vthd = (unsigned*)Vth;
    unsigned* vtld = (unsigned*)Vtl;
#pragma unroll
    for (int x = 0; x < 16; x += 4) {
      float4 a4 = *(const float4*)(v0 + x);
      float4 b4 = *(const float4*)(v1 + x);
      const float* af = (const float*)&a4;
      const float* bf = (const float*)&b4;
#pragma unroll
      for (int e = 0; e < 4; ++e) {
        const int d = wq * 16 + x + e;
        short ha = f2bf(af[e]), hb = f2bf(bf[e]);
        float la = af[e] - bf2f(ha), lb = bf[e] - bf2f(hb);
        vthd[d * 68 + c2] = pack2(ha, hb);
        vtld[d * 68 + c2] = pack2(f2bf(la), f2bf(lb));
      }
    }
  }
  if (tid < 64) Lr[tid] = lall[(size_t)b * S + tjs[tid]];
  __syncthreads();
  if (tid < 128)
    scale[tid] = SM_SCALE / fmaxf(sqrtf(scp[tid][0] + scp[tid][1]), 1e-12f);
  __syncthreads();

  const int w = tid >> 6, l = tid & 63, lr = l & 15, lg = l >> 4;
  f32x4 acc[8];
#pragma unroll
  for (int nt = 0; nt < 8; ++nt) acc[nt] = (f32x4){0.f, 0.f, 0.f, 0.f};
#pragma unroll
  for (int kt = 0; kt < 2; ++kt) {
    const int ko = kt * 32 + lg * 8;
    bf16x8 Ah = *(const bf16x8*)&KQh[16 * w + lr][ko];
    bf16x8 Al = *(const bf16x8*)&KQl[16 * w + lr][ko];
#pragma unroll
    for (int nt = 0; nt < 8; ++nt) {
      bf16x8 Bh = *(const bf16x8*)&KQh[16 * nt + lr][ko];
      bf16x8 Bl = *(const bf16x8*)&KQl[16 * nt + lr][ko];
      acc[nt] = MFMA(Ah, Bh, acc[nt]);
      acc[nt] = MFMA(Ah, Bl, acc[nt]);
      acc[nt] = MFMA(Al, Bh, acc[nt]);
    }
  }

  float sc8[8]; int tc8[8];
#pragma unroll
  for (int nt = 0; nt < 8; ++nt) {
    int col = 16 * nt + lr;
    sc8[nt] = scale[col]; tc8[nt] = tjs[col];
  }
  int trow[4]; float Lv[4];
#pragma unroll
  for (int r = 0; r < 4; ++r) {
    const int row = 16 * w + 4 * lg + r;
    trow[r] = tjs[row]; Lv[r] = Lr[row];
  }
  __syncthreads();   // all KQ reads complete before Pf overwrite

#pragma unroll
  for (int nt = 0; nt < 8; ++nt) {
    const int col = 16 * nt + lr;
#pragma unroll
    for (int r = 0; r < 4; ++r) {
      float val = (tc8[nt] == trow[r]) ? SELF_VAL : acc[nt][r] * sc8[nt];
      Pf[(16 * w + 4 * lg + r) * 132 + col] = expf(val - Lv[r]);
    }
  }
  __syncthreads();

  f32x4 o[4];
#pragma unroll
  for (int nt = 0; nt < 4; ++nt) o[nt] = (f32x4){0.f, 0.f, 0.f, 0.f};
#pragma unroll
  for (int kt = 0; kt < 4; ++kt) {
    const float* pr = Pf + (16 * w + lr) * 132 + kt * 32 + lg * 8;
    float4 pa = *(const float4*)pr;
    float4 pb = *(const float4*)(pr + 4);
    const float* paf = (const float*)&pa;
    const float* pbf = (const float*)&pb;
    frag_u Ph, Pl;
#pragma unroll
    for (int e = 0; e < 4; ++e) {
      short hh = f2bf(paf[e]);
      Ph.s[e] = hh; Pl.s[e] = f2bf(paf[e] - bf2f(hh));
      short h2 = f2bf(pbf[e]);
      Ph.s[e + 4] = h2; Pl.s[e + 4] = f2bf(pbf[e] - bf2f(h2));
    }
#pragma unroll
    for (int nt = 0; nt < 4; ++nt) {
      bf16x8 Bh = *(const bf16x8*)&Vth[16 * nt + lr][kt * 32 + lg * 8];
      bf16x8 Bl = *(const bf16x8*)&Vtl[16 * nt + lr][kt * 32 + lg * 8];
      o[nt] = MFMA(Ph.v, Bh, o[nt]);
      o[nt] = MFMA(Ph.v, Bl, o[nt]);
      o[nt] = MFMA(Pl.v, Bh, o[nt]);
    }
  }

  if (obuf != nullptr) {
    float* dst = obuf + ((size_t)(b * H + h)) * S * 64;
#pragma unroll
    for (int nt = 0; nt < 4; ++nt)
#pragma unroll
      for (int r = 0; r < 4; ++r)
        dst[(size_t)trow[r] * 64 + 16 * nt + lr] = o[nt][r];
  } else {
#pragma unroll
    for (int nt = 0; nt < 4; ++nt)
#pragma unroll
      for (int r = 0; r < 4; ++r)
        atomicAdd(&out[((size_t)b * S + trow[r]) * 64 + 16 * nt + lr], o[nt][r]);
  }
}

// ---------------------------------------------------------------------------
// K5: out[b,t,d] = sum_h obuf[b,h,t,d] (fully coalesced)
// ---------------------------------------------------------------------------
__global__ __launch_bounds__(256) void k_combine(const float* __restrict__ obuf,
                                                 float* __restrict__ out) {
  const size_t idx = (size_t)blockIdx.x * 256 + threadIdx.x;  // over B*S*64
  const int d = idx & 63;
  const size_t bt = idx >> 6;
  const int b = (int)(bt >> 13), t = (int)(bt & (S - 1));
  float s = 0.f;
#pragma unroll
  for (int h = 0; h < 8; ++h)
    s += obuf[(((size_t)b * H + h) * S + t) * 64 + d];
  out[idx] = s;
}

// ---------------------------------------------------------------------------
extern "C" void kernel_launch(void* const* d_in, const int* in_sizes, int n_in,
                              void* d_out, int out_size, void* d_ws, size_t ws_size,
                              hipStream_t stream) {
  const float* qk  = (const float*)d_in[0];
  const float* v   = (const float*)d_in[1];
  const float* rot = (const float*)d_in[2];
  float* out = (float*)d_out;
  char* ws = (char*)d_ws;

  int*   buckets = (int*)ws;                             // 4 MB
  int*   st      = (int*)(ws + ((size_t)4 << 20));       // 4 MB
  float* lse     = (float*)(ws + ((size_t)8 << 20));     // 4 MB
  float* lall    = (float*)(ws + ((size_t)12 << 20));    // 512 KB
  float* obuf    = (float*)(ws + ((size_t)13 << 20));    // 256 MB if available
  const size_t obuf_bytes = (size_t)B * H * S * 64 * sizeof(float);
  const bool use_obuf = ws_size >= (((size_t)13 << 20) + obuf_bytes);

  k_hash<<<dim3(S / 256, B * H), 256, 0, stream>>>(qk, rot, buckets);
  k_sort<<<B * H, 64, 0, stream>>>(buckets, st);
  k_att1<<<dim3(NCH, B), 256, 0, stream>>>(qk, st, lse);
  k_lall<<<(B * S) / 256, 256, 0, stream>>>(lse, lall);
  if (use_obuf) {
    k_att2<<<dim3(NCH, B), 256, 0, stream>>>(qk, v, st, lall, obuf, out);
    k_combine<<<(B * S * 64) / 256, 256, 0, stream>>>(obuf, out);
  } else {
    hipMemsetAsync(d_out, 0, (size_t)B * S * 64 * sizeof(float), stream);
    k_att2<<<dim3(NCH, B), 256, 0, stream>>>(qk, v, st, lall, nullptr, out);
  }
}

// Round 4
// 716.591 us; speedup vs baseline: 7.1435x; 1.3716x over previous
//
#include <hip/hip_runtime.h>
#include <math.h>

constexpr int B   = 16;
constexpr int S   = 8192;
constexpr int H   = 8;
constexpr int NCH = 1024;      // chunks per batch (H * n_buckets)
constexpr float SM_SCALE = 0.125f;
constexpr float SELF_VAL = -5e4f;

typedef __bf16 bf16x8 __attribute__((ext_vector_type(8)));
typedef float  f32x4  __attribute__((ext_vector_type(4)));
union frag_u { bf16x8 v; short s[8]; };

__device__ __forceinline__ short f2bf(float x) {
  unsigned u = __float_as_uint(x);
  unsigned r = u + 0x7fffu + ((u >> 16) & 1u);
  return (short)(r >> 16);
}
__device__ __forceinline__ float bf2f(short h) {
  return __uint_as_float(((unsigned)(unsigned short)h) << 16);
}
__device__ __forceinline__ unsigned pack2(short a, short b) {
  return ((unsigned)(unsigned short)a) | (((unsigned)(unsigned short)b) << 16);
}

#define MFMA(a, bb, c) __builtin_amdgcn_mfma_f32_16x16x32_bf16((a), (bb), (c), 0, 0, 0)

// ---------------------------------------------------------------------------
// K1: LSH hashing via MFMA (the ONE change vs R2). Per block: 64 tokens of
// one (b,h). C[s][i] = sum_f qk[s][f]*R[f][i]; bucket = argmax over [C,-C].
// Split-bf16 + (best,second) margin; fp64 cooperative fallback when margin
// < 1e-2 -> decisions identical to the fp32/fp64 reference.
// ---------------------------------------------------------------------------
__global__ __launch_bounds__(256) void k_hash(const float* __restrict__ qk,
                                              const float* __restrict__ rot,
                                              int* __restrict__ buckets) {
  const int bh = blockIdx.y;
  const int b = bh >> 3, h = bh & 7;
  const int s0 = blockIdx.x * 64;
  __shared__ __align__(16) short Qh[64][72];
  __shared__ __align__(16) short Ql[64][72];
  __shared__ __align__(16) short Rh[64][72];   // Rt[i][f] = R[f][i]
  __shared__ __align__(16) short Rl[64][72];
  const int tid = threadIdx.x;

  { // stage Q rows (split bf16 hi/lo)
    const int j = tid >> 2, q4 = tid & 3;
    const float* src = qk + ((size_t)b * S + s0 + j) * 64 + q4 * 16;
    unsigned* dh = (unsigned*)&Qh[j][q4 * 16];
    unsigned* dl = (unsigned*)&Ql[j][q4 * 16];
#pragma unroll
    for (int x = 0; x < 16; x += 4) {
      float4 v4 = *(const float4*)(src + x);
      const float* vf = (const float*)&v4;
      short h0 = f2bf(vf[0]), h1 = f2bf(vf[1]), h2 = f2bf(vf[2]), h3 = f2bf(vf[3]);
      dh[x >> 1]       = pack2(h0, h1);
      dh[(x >> 1) + 1] = pack2(h2, h3);
      dl[x >> 1]       = pack2(f2bf(vf[0] - bf2f(h0)), f2bf(vf[1] - bf2f(h1)));
      dl[(x >> 1) + 1] = pack2(f2bf(vf[2] - bf2f(h2)), f2bf(vf[3] - bf2f(h3)));
    }
  }
  // stage R transposed (coalesced reads over i)
#pragma unroll
  for (int k = 0; k < 16; ++k) {
    int idx = tid + k * 256;
    int f = idx >> 6, i = idx & 63;
    float x = rot[(((size_t)b * 64 + f) * 8 + h) * 64 + i];
    short hi = f2bf(x);
    Rh[i][f] = hi;
    Rl[i][f] = f2bf(x - bf2f(hi));
  }
  __syncthreads();

  const int w = tid >> 6, l = tid & 63, lr = l & 15, lg = l >> 4;
  f32x4 acc[4];
#pragma unroll
  for (int nt = 0; nt < 4; ++nt) acc[nt] = (f32x4){0.f, 0.f, 0.f, 0.f};
#pragma unroll
  for (int kt = 0; kt < 2; ++kt) {
    const int ko = kt * 32 + lg * 8;
    bf16x8 Ah = *(const bf16x8*)&Qh[16 * w + lr][ko];
    bf16x8 Al = *(const bf16x8*)&Ql[16 * w + lr][ko];
#pragma unroll
    for (int nt = 0; nt < 4; ++nt) {
      bf16x8 Bh = *(const bf16x8*)&Rh[16 * nt + lr][ko];
      bf16x8 Bl = *(const bf16x8*)&Rl[16 * nt + lr][ko];
      acc[nt] = MFMA(Ah, Bh, acc[nt]);
      acc[nt] = MFMA(Ah, Bl, acc[nt]);
      acc[nt] = MFMA(Al, Bh, acc[nt]);
    }
  }

#pragma unroll
  for (int r = 0; r < 4; ++r) {
    const int row = 16 * w + 4 * lg + r;
    float best = -3e38f, second = -3e38f; int bidx = 0;
#pragma unroll
    for (int nt = 0; nt < 4; ++nt) {
      float vv = acc[nt][r];
      int ip = 16 * nt + lr;
      if (vv > best) { second = best; best = vv; bidx = ip; }
      else if (vv >= second) second = vv;
      float nv = -vv;
      if (nv > best) { second = best; best = nv; bidx = ip + 64; }
      else if (nv >= second) second = nv;
    }
    // butterfly over the 16-lane row group, smaller idx wins ties
#pragma unroll
    for (int dm = 1; dm < 16; dm <<= 1) {
      float ob = __shfl_xor(best, dm);
      float os = __shfl_xor(second, dm);
      int   oi = __shfl_xor(bidx, dm);
      float ns = fmaxf(fminf(best, ob), fmaxf(second, os));
      if (ob > best || (ob == best && oi < bidx)) bidx = oi;
      best = fmaxf(best, ob);
      second = ns;
    }
    if (best - second < 1e-2f) {
      // cooperative fp64 recompute: lane lr handles i = lr + 16*ii
      const float* qrow = qk + ((size_t)b * S + s0 + row) * 64;
      double db = -1e300; int di = 0;
      for (int ii = 0; ii < 4; ++ii) {
        const int i = lr + 16 * ii;
        double a = 0.0;
        for (int f = 0; f < 64; ++f)
          a += (double)qrow[f] * (double)rot[(((size_t)b * 64 + f) * 8 + h) * 64 + i];
        if (a > db || (a == db && i < di)) { db = a; di = i; }
        double na = -a;
        if (na > db || (na == db && (i + 64) < di)) { db = na; di = i + 64; }
      }
      for (int dm = 1; dm < 16; dm <<= 1) {
        double od = __shfl_xor(db, dm);
        int    oi = __shfl_xor(di, dm);
        if (od > db || (od == db && oi < di)) { db = od; di = oi; }
      }
      bidx = di;
    }
    if (lr == 0) buckets[(size_t)bh * S + s0 + row] = bidx;
  }
}

// ---------------------------------------------------------------------------
// K2: stable counting sort per (b,h) (R2 verbatim)
// ---------------------------------------------------------------------------
__global__ __launch_bounds__(64) void k_sort(const int* __restrict__ buckets,
                                             int* __restrict__ st) {
  const int bh = blockIdx.x;
  __shared__ int hist[128][65];
  __shared__ int base[128];
  const int t = threadIdx.x;
  for (int v = 0; v < 128; ++v) hist[v][t] = 0;
  __syncthreads();
  const int* bk = buckets + (size_t)bh * S;
  for (int k = 0; k < 128; ++k) hist[bk[t * 128 + k]][t]++;
  __syncthreads();
  for (int v = t; v < 128; v += 64) {
    int run = 0;
    for (int tt = 0; tt < 64; ++tt) { int x = hist[v][tt]; hist[v][tt] = run; run += x; }
    base[v] = run;
  }
  __syncthreads();
  if (t == 0) {
    int run = 0;
    for (int v = 0; v < 128; ++v) { int x = base[v]; base[v] = run; run += x; }
  }
  __syncthreads();
  int* out = st + (size_t)bh * S;
  for (int k = 0; k < 128; ++k) {
    int item = t * 128 + k;
    int v = bk[item];
    out[base[v] + hist[v][t]++] = item;
  }
}

__device__ __forceinline__ int col_token(const int* __restrict__ st, int b,
                                         int c, int j) {
  int cc = (j < 64) ? c : ((c + NCH - 1) & (NCH - 1));
  int r = j & 63;
  int h = cc >> 7;
  int slot = ((cc & 127) << 6) + r;
  return st[((size_t)b * H + h) * S + slot];
}

// ---------------------------------------------------------------------------
// Shared staging (R2 verbatim)
// ---------------------------------------------------------------------------
__device__ __forceinline__ void stage_kq(const float* __restrict__ qk, int b,
                                         const int* tjs, short (*KQh)[72],
                                         short (*KQl)[72], float (*scp)[2],
                                         int tid) {
  const int j = tid >> 1, hf = tid & 1;
  const float* src = qk + ((size_t)b * S + tjs[j]) * 64 + hf * 32;
  unsigned* dh = (unsigned*)&KQh[j][hf * 32];
  unsigned* dl = (unsigned*)&KQl[j][hf * 32];
  float ss = 0.f;
#pragma unroll
  for (int x = 0; x < 32; x += 4) {
    float4 v4 = *(const float4*)(src + x);
    const float* vf = (const float*)&v4;
    short h0 = f2bf(vf[0]), h1 = f2bf(vf[1]), h2 = f2bf(vf[2]), h3 = f2bf(vf[3]);
    float l0 = vf[0] - bf2f(h0), l1 = vf[1] - bf2f(h1);
    float l2 = vf[2] - bf2f(h2), l3 = vf[3] - bf2f(h3);
    dh[(x >> 1)]     = pack2(h0, h1);
    dh[(x >> 1) + 1] = pack2(h2, h3);
    dl[(x >> 1)]     = pack2(f2bf(l0), f2bf(l1));
    dl[(x >> 1) + 1] = pack2(f2bf(l2), f2bf(l3));
    ss = fmaf(vf[0], vf[0], ss); ss = fmaf(vf[1], vf[1], ss);
    ss = fmaf(vf[2], vf[2], ss); ss = fmaf(vf[3], vf[3], ss);
  }
  scp[j][hf] = ss;
}

// ---------------------------------------------------------------------------
// K3a: MFMA dots + per-row logsumexp -> lse_buf[b,h,t] (R2 verbatim)
// ---------------------------------------------------------------------------
__global__ __launch_bounds__(256) void k_att1(const float* __restrict__ qk,
                                              const int* __restrict__ st,
                                              float* __restrict__ lse_buf) {
  const int c = blockIdx.x, b = blockIdx.y;
  const int tid = threadIdx.x;
  __shared__ __align__(16) char smem[38912];
  short (*KQh)[72] = (short(*)[72])(smem);
  short (*KQl)[72] = (short(*)[72])(smem + 18432);
  float* scale     = (float*)(smem + 36864);
  int*   tjs       = (int*)(smem + 37376);
  float (*scp)[2]  = (float(*)[2])(smem + 37888);

  if (tid < 128) tjs[tid] = col_token(st, b, c, tid);
  __syncthreads();
  stage_kq(qk, b, tjs, KQh, KQl, scp, tid);
  __syncthreads();
  if (tid < 128)
    scale[tid] = SM_SCALE / fmaxf(sqrtf(scp[tid][0] + scp[tid][1]), 1e-12f);
  __syncthreads();

  const int w = tid >> 6, l = tid & 63, lr = l & 15, lg = l >> 4;
  f32x4 acc[8];
#pragma unroll
  for (int nt = 0; nt < 8; ++nt) acc[nt] = (f32x4){0.f, 0.f, 0.f, 0.f};
#pragma unroll
  for (int kt = 0; kt < 2; ++kt) {
    const int ko = kt * 32 + lg * 8;
    bf16x8 Ah = *(const bf16x8*)&KQh[16 * w + lr][ko];
    bf16x8 Al = *(const bf16x8*)&KQl[16 * w + lr][ko];
#pragma unroll
    for (int nt = 0; nt < 8; ++nt) {
      bf16x8 Bh = *(const bf16x8*)&KQh[16 * nt + lr][ko];
      bf16x8 Bl = *(const bf16x8*)&KQl[16 * nt + lr][ko];
      acc[nt] = MFMA(Ah, Bh, acc[nt]);
      acc[nt] = MFMA(Ah, Bl, acc[nt]);
      acc[nt] = MFMA(Al, Bh, acc[nt]);
    }
  }

  float sc8[8]; int tc8[8];
#pragma unroll
  for (int nt = 0; nt < 8; ++nt) {
    int col = 16 * nt + lr;
    sc8[nt] = scale[col]; tc8[nt] = tjs[col];
  }
  const int h = c >> 7;
#pragma unroll
  for (int r = 0; r < 4; ++r) {
    const int row = 16 * w + 4 * lg + r;
    const int trow = tjs[row];
    float v8[8]; float m = -3e38f;
#pragma unroll
    for (int nt = 0; nt < 8; ++nt) {
      float val = (tc8[nt] == trow) ? SELF_VAL : acc[nt][r] * sc8[nt];
      v8[nt] = val; m = fmaxf(m, val);
    }
#pragma unroll
    for (int dm = 1; dm < 16; dm <<= 1) m = fmaxf(m, __shfl_xor(m, dm));
    float s = 0.f;
#pragma unroll
    for (int nt = 0; nt < 8; ++nt) s += expf(v8[nt] - m);
#pragma unroll
    for (int dm = 1; dm < 16; dm <<= 1) s += __shfl_xor(s, dm);
    if (lr == 0) lse_buf[((size_t)b * H + h) * S + trow] = m + logf(s);
  }
}

// ---------------------------------------------------------------------------
// K4: L_all over hash rounds (R2 verbatim)
// ---------------------------------------------------------------------------
__global__ __launch_bounds__(256) void k_lall(const float* __restrict__ lse_buf,
                                              float* __restrict__ lall) {
  const int idx = blockIdx.x * 256 + threadIdx.x;   // b*S + t
  const int b = idx >> 13, t = idx & (S - 1);
  float l[8];
#pragma unroll
  for (int h = 0; h < 8; ++h) l[h] = lse_buf[((size_t)b * H + h) * S + t];
  float m = l[0];
#pragma unroll
  for (int h = 1; h < 8; ++h) m = fmaxf(m, l[h]);
  float s = 0.f;
#pragma unroll
  for (int h = 0; h < 8; ++h) s += expf(l[h] - m);
  lall[idx] = m + logf(s);
}

// ---------------------------------------------------------------------------
// K3b (R2 verbatim): MFMA dots -> P = exp(val - L_all) -> MFMA PV.
// ---------------------------------------------------------------------------
__global__ __launch_bounds__(256) void k_att2(const float* __restrict__ qk,
                                              const float* __restrict__ v,
                                              const int* __restrict__ st,
                                              const float* __restrict__ lall,
                                              float* __restrict__ obuf,
                                              float* __restrict__ out) {
  const int c = blockIdx.x, b = blockIdx.y;
  const int tid = threadIdx.x;
  const int h = c >> 7;
  __shared__ __align__(16) char smem[73984];
  short (*KQh)[72]  = (short(*)[72])(smem);
  short (*KQl)[72]  = (short(*)[72])(smem + 18432);
  short (*Vth)[136] = (short(*)[136])(smem + 36864);
  short (*Vtl)[136] = (short(*)[136])(smem + 54272);
  float* scale      = (float*)(smem + 71680);
  int*   tjs        = (int*)(smem + 72192);
  float* Lr         = (float*)(smem + 72704);
  float (*scp)[2]   = (float(*)[2])(smem + 72960);
  float* Pf = (float*)smem;   // [64][132] fp32, overlays KQh+KQl after dots

  if (tid < 128) tjs[tid] = col_token(st, b, c, tid);
  __syncthreads();
  stage_kq(qk, b, tjs, KQh, KQl, scp, tid);
  { // V staged transposed: Vt[d][col] bf16 hi/lo, dword-packed col pairs
    const int c2 = tid & 63, wq = tid >> 6;
    const int j0 = 2 * c2, j1 = j0 + 1;
    const float* v0 = v + ((size_t)b * S + tjs[j0]) * 64 + wq * 16;
    const float* v1 = v + ((size_t)b * S + tjs[j1]) * 64 + wq * 16;
    unsigned* vthd = (unsigned*)Vth;
    unsigned* vtld = (unsigned*)Vtl;
#pragma unroll
    for (int x = 0; x < 16; x += 4) {
      float4 a4 = *(const float4*)(v0 + x);
      float4 b4 = *(const float4*)(v1 + x);
      const float* af = (const float*)&a4;
      const float* bf = (const float*)&b4;
#pragma unroll
      for (int e = 0; e < 4; ++e) {
        const int d = wq * 16 + x + e;
        short ha = f2bf(af[e]), hb = f2bf(bf[e]);
        float la = af[e] - bf2f(ha), lb = bf[e] - bf2f(hb);
        vthd[d * 68 + c2] = pack2(ha, hb);
        vtld[d * 68 + c2] = pack2(f2bf(la), f2bf(lb));
      }
    }
  }
  if (tid < 64) Lr[tid] = lall[(size_t)b * S + tjs[tid]];
  __syncthreads();
  if (tid < 128)
    scale[tid] = SM_SCALE / fmaxf(sqrtf(scp[tid][0] + scp[tid][1]), 1e-12f);
  __syncthreads();

  const int w = tid >> 6, l = tid & 63, lr = l & 15, lg = l >> 4;
  f32x4 acc[8];
#pragma unroll
  for (int nt = 0; nt < 8; ++nt) acc[nt] = (f32x4){0.f, 0.f, 0.f, 0.f};
#pragma unroll
  for (int kt = 0; kt < 2; ++kt) {
    const int ko = kt * 32 + lg * 8;
    bf16x8 Ah = *(const bf16x8*)&KQh[16 * w + lr][ko];
    bf16x8 Al = *(const bf16x8*)&KQl[16 * w + lr][ko];
#pragma unroll
    for (int nt = 0; nt < 8; ++nt) {
      bf16x8 Bh = *(const bf16x8*)&KQh[16 * nt + lr][ko];
      bf16x8 Bl = *(const bf16x8*)&KQl[16 * nt + lr][ko];
      acc[nt] = MFMA(Ah, Bh, acc[nt]);
      acc[nt] = MFMA(Ah, Bl, acc[nt]);
      acc[nt] = MFMA(Al, Bh, acc[nt]);
    }
  }

  float sc8[8]; int tc8[8];
#pragma unroll
  for (int nt = 0; nt < 8; ++nt) {
    int col = 16 * nt + lr;
    sc8[nt] = scale[col]; tc8[nt] = tjs[col];
  }
  int trow[4]; float Lv[4];
#pragma unroll
  for (int r = 0; r < 4; ++r) {
    const int row = 16 * w + 4 * lg + r;
    trow[r] = tjs[row]; Lv[r] = Lr[row];
  }
  __syncthreads();   // all KQ reads complete before Pf overwrite

#pragma unroll
  for (int nt = 0; nt < 8; ++nt) {
    const int col = 16 * nt + lr;
#pragma unroll
    for (int r = 0; r < 4; ++r) {
      float val = (tc8[nt] == trow[r]) ? SELF_VAL : acc[nt][r] * sc8[nt];
      Pf[(16 * w + 4 * lg + r) * 132 + col] = expf(val - Lv[r]);
    }
  }
  __syncthreads();

  f32x4 o[4];
#pragma unroll
  for (int nt = 0; nt < 4; ++nt) o[nt] = (f32x4){0.f, 0.f, 0.f, 0.f};
#pragma unroll
  for (int kt = 0; kt < 4; ++kt) {
    const float* pr = Pf + (16 * w + lr) * 132 + kt * 32 + lg * 8;
    float4 pa = *(const float4*)pr;
    float4 pb = *(const float4*)(pr + 4);
    const float* paf = (const float*)&pa;
    const float* pbf = (const float*)&pb;
    frag_u Ph, Pl;
#pragma unroll
    for (int e = 0; e < 4; ++e) {
      short hh = f2bf(paf[e]);
      Ph.s[e] = hh; Pl.s[e] = f2bf(paf[e] - bf2f(hh));
      short h2 = f2bf(pbf[e]);
      Ph.s[e + 4] = h2; Pl.s[e + 4] = f2bf(pbf[e] - bf2f(h2));
    }
#pragma unroll
    for (int nt = 0; nt < 4; ++nt) {
      bf16x8 Bh = *(const bf16x8*)&Vth[16 * nt + lr][kt * 32 + lg * 8];
      bf16x8 Bl = *(const bf16x8*)&Vtl[16 * nt + lr][kt * 32 + lg * 8];
      o[nt] = MFMA(Ph.v, Bh, o[nt]);
      o[nt] = MFMA(Ph.v, Bl, o[nt]);
      o[nt] = MFMA(Pl.v, Bh, o[nt]);
    }
  }

  if (obuf != nullptr) {
    float* dst = obuf + ((size_t)(b * H + h)) * S * 64;
#pragma unroll
    for (int nt = 0; nt < 4; ++nt)
#pragma unroll
      for (int r = 0; r < 4; ++r)
        dst[(size_t)trow[r] * 64 + 16 * nt + lr] = o[nt][r];
  } else {
#pragma unroll
    for (int nt = 0; nt < 4; ++nt)
#pragma unroll
      for (int r = 0; r < 4; ++r)
        atomicAdd(&out[((size_t)b * S + trow[r]) * 64 + 16 * nt + lr], o[nt][r]);
  }
}

// ---------------------------------------------------------------------------
// K5: out[b,t,d] = sum_h obuf[b,h,t,d] (R2 verbatim)
// ---------------------------------------------------------------------------
__global__ __launch_bounds__(256) void k_combine(const float* __restrict__ obuf,
                                                 float* __restrict__ out) {
  const size_t idx = (size_t)blockIdx.x * 256 + threadIdx.x;  // over B*S*64
  const int d = idx & 63;
  const size_t bt = idx >> 6;
  const int b = (int)(bt >> 13), t = (int)(bt & (S - 1));
  float s = 0.f;
#pragma unroll
  for (int h = 0; h < 8; ++h)
    s += obuf[(((size_t)b * H + h) * S + t) * 64 + d];
  out[idx] = s;
}

// ---------------------------------------------------------------------------
extern "C" void kernel_launch(void* const* d_in, const int* in_sizes, int n_in,
                              void* d_out, int out_size, void* d_ws, size_t ws_size,
                              hipStream_t stream) {
  const float* qk  = (const float*)d_in[0];
  const float* v   = (const float*)d_in[1];
  const float* rot = (const float*)d_in[2];
  float* out = (float*)d_out;
  char* ws = (char*)d_ws;

  int*   buckets = (int*)ws;                             // 4 MB
  int*   st      = (int*)(ws + ((size_t)4 << 20));       // 4 MB
  float* lse     = (float*)(ws + ((size_t)8 << 20));     // 4 MB
  float* lall    = (float*)(ws + ((size_t)12 << 20));    // 512 KB
  float* obuf    = (float*)(ws + ((size_t)13 << 20));    // 268.4 MB if available
  const size_t obuf_bytes = (size_t)B * H * S * 64 * sizeof(float);
  const bool use_obuf = ws_size >= (((size_t)13 << 20) + obuf_bytes);

  k_hash<<<dim3(S / 64, B * H), 256, 0, stream>>>(qk, rot, buckets);
  k_sort<<<B * H, 64, 0, stream>>>(buckets, st);
  k_att1<<<dim3(NCH, B), 256, 0, stream>>>(qk, st, lse);
  k_lall<<<(B * S) / 256, 256, 0, stream>>>(lse, lall);
  if (use_obuf) {
    k_att2<<<dim3(NCH, B), 256, 0, stream>>>(qk, v, st, lall, obuf, out);
    k_combine<<<(B * S * 64) / 256, 256, 0, stream>>>(obuf, out);
  } else {
    hipMemsetAsync(d_out, 0, (size_t)B * S * 64 * sizeof(float), stream);
    k_att2<<<dim3(NCH, B), 256, 0, stream>>>(qk, v, st, lall, nullptr, out);
  }
}